// Round 1
// baseline (578.400 us; speedup 1.0000x reference)
//
#include <hip/hip_runtime.h>
#include <hip/hip_bf16.h>

#define BATCH 2
#define LSEQ 4096
#define M (BATCH*LSEQ)   // 8192 rows
#define D 128
#define P 64
#define NL 2
#define VOCAB 32000
#define DFF 512

typedef __attribute__((ext_vector_type(8))) short bf16x8_t;
typedef __attribute__((ext_vector_type(4))) float f32x4_t;

__device__ inline unsigned short f2bf(float f) {
    unsigned int u = __float_as_uint(f);
    unsigned int r = (u + 0x7fffu + ((u >> 16) & 1u)) >> 16;
    return (unsigned short)r;
}
__device__ inline float bf2f(unsigned short u) {
    return __uint_as_float(((unsigned int)u) << 16);
}

// h[row][d] = embed[tokens[row]][d] + pos[row % LSEQ][d]; also hb = bf16(h)
__global__ void k_embed(const int* __restrict__ tokens, const float* __restrict__ embed,
                        const float* __restrict__ pos, float* __restrict__ h,
                        unsigned short* __restrict__ hb) {
    int gid = blockIdx.x * blockDim.x + threadIdx.x;   // over M*32 float4s
    int row = gid >> 5;
    int d4  = gid & 31;
    int l = row & (LSEQ - 1);
    int tok = tokens[row];
    float4 a = ((const float4*)(embed + (size_t)tok * D))[d4];
    float4 b = ((const float4*)(pos + (size_t)l * D))[d4];
    a.x += b.x; a.y += b.y; a.z += b.z; a.w += b.w;
    ((float4*)(h + (size_t)row * D))[d4] = a;
    ushort4 u; u.x = f2bf(a.x); u.y = f2bf(a.y); u.z = f2bf(a.z); u.w = f2bf(a.w);
    ((ushort4*)(hb + (size_t)row * D))[d4] = u;
}

// Wout [D][VOCAB] f32  ->  WT [VOCAB][D] bf16
__global__ void k_wt(const float* __restrict__ W, unsigned short* __restrict__ WT) {
    __shared__ float tile[32][33];
    int v0 = blockIdx.x * 32, d0 = blockIdx.y * 32;
    int tx = threadIdx.x, ty = threadIdx.y;
    for (int i = ty; i < 32; i += 8)
        tile[i][tx] = W[(size_t)(d0 + i) * VOCAB + v0 + tx];
    __syncthreads();
    for (int i = ty; i < 32; i += 8)
        WT[(size_t)(v0 + i) * D + d0 + tx] = f2bf(tile[tx][i]);
}

// BqkvT[l][256][128] bf16:
//  rows 0-63   : WqpT[p][d] = sum_e Wq[l][d][e] * proj[l][e][p]
//  rows 64-127 : WkpT[p][d]
//  rows 128-255: WvT[o][d]  = Wv[l][d][o]
__global__ void k_prep_qkv(const float* __restrict__ Wq, const float* __restrict__ Wk,
                           const float* __restrict__ Wv, const float* __restrict__ proj,
                           unsigned short* __restrict__ out) {
    int r = blockIdx.x;       // 0..255
    int l = blockIdx.y;
    int d = threadIdx.x;      // 128
    const float* WqL = Wq + (size_t)l * D * D;
    const float* WkL = Wk + (size_t)l * D * D;
    const float* WvL = Wv + (size_t)l * D * D;
    const float* pjL = proj + (size_t)l * D * P;
    float val;
    if (r < 128) {
        const float* W = (r < 64) ? WqL : WkL;
        int p = r & 63;
        float s = 0.f;
        for (int e = 0; e < D; e++) s = fmaf(W[d * D + e], pjL[e * P + p], s);
        val = s;
    } else {
        val = WvL[d * D + (r - 128)];
    }
    out[((size_t)l * 256 + r) * D + d] = f2bf(val);
}

// W1T[l][n][d] = W1[l][d][n]  (bf16)
__global__ void k_prep_w1t(const float* __restrict__ W1, unsigned short* __restrict__ W1T) {
    int n = blockIdx.x;   // 512
    int l = blockIdx.y;
    int d = threadIdx.x;  // 128
    W1T[((size_t)l * DFF + n) * D + d] = f2bf(W1[((size_t)l * D + d) * DFF + n]);
}

// W2T[l][n][f] = W2[l][f][n]  (bf16)
__global__ void k_prep_w2t(const float* __restrict__ W2, unsigned short* __restrict__ W2T) {
    int n = blockIdx.x;   // 128
    int l = blockIdx.y;
    int f = threadIdx.x;  // 512
    W2T[((size_t)l * D + n) * DFF + f] = f2bf(W2[((size_t)l * DFF + f) * D + n]);
}

// Fused projections: C[M x 256] = hb @ BqkvT^T ; cols 0-63 -> qp=elu(x)+1 (f32),
// 64-127 -> kp (f32), 128-255 -> vb (bf16). Tile 32 rows x 256 cols, 4 waves.
__global__ __launch_bounds__(256) void k_qkvp(const unsigned short* __restrict__ hb,
                                              const unsigned short* __restrict__ Bt,
                                              float* __restrict__ qp, float* __restrict__ kp,
                                              unsigned short* __restrict__ vb) {
    int r0 = blockIdx.x * 32;
    int wid = threadIdx.x >> 6;
    int lane = threadIdx.x & 63;
    int c0 = wid * 64;
    int lr = lane & 15;
    int lk = (lane >> 4) * 8;
    const short* Ap = (const short*)hb;
    const short* Bp = (const short*)Bt;
    f32x4_t acc[2][4] = {};
    #pragma unroll
    for (int kc = 0; kc < 4; kc++) {
        bf16x8_t af[2], bfr[4];
        #pragma unroll
        for (int mi = 0; mi < 2; mi++)
            af[mi] = *(const bf16x8_t*)(Ap + (size_t)(r0 + mi * 16 + lr) * D + kc * 32 + lk);
        #pragma unroll
        for (int ni = 0; ni < 4; ni++)
            bfr[ni] = *(const bf16x8_t*)(Bp + (size_t)(c0 + ni * 16 + lr) * D + kc * 32 + lk);
        #pragma unroll
        for (int mi = 0; mi < 2; mi++)
            #pragma unroll
            for (int ni = 0; ni < 4; ni++)
                acc[mi][ni] = __builtin_amdgcn_mfma_f32_16x16x32_bf16(af[mi], bfr[ni], acc[mi][ni], 0, 0, 0);
    }
    int orow = (lane >> 4) * 4;
    if (wid < 2) {  // qp / kp with elu(x)+1, f32 out
        float* out = (wid == 0) ? qp : kp;
        #pragma unroll
        for (int mi = 0; mi < 2; mi++)
            #pragma unroll
            for (int ni = 0; ni < 4; ni++)
                #pragma unroll
                for (int j = 0; j < 4; j++) {
                    float x = acc[mi][ni][j];
                    float e = x > 0.f ? x + 1.f : __expf(x);
                    out[(size_t)(r0 + mi * 16 + orow + j) * P + ni * 16 + lr] = e;
                }
    } else {        // vb bf16 out, cols (wid-2)*64 + ...
        int cb = (wid - 2) * 64;
        #pragma unroll
        for (int mi = 0; mi < 2; mi++)
            #pragma unroll
            for (int ni = 0; ni < 4; ni++)
                #pragma unroll
                for (int j = 0; j < 4; j++)
                    vb[(size_t)(r0 + mi * 16 + orow + j) * D + cb + ni * 16 + lr] = f2bf(acc[mi][ni][j]);
    }
}

// partial kv: part[b][ch][p][d] = sum_{l in chunk} kp[b][l][p] * vb[b][l][d]
__global__ void k_kvpart(const float* __restrict__ kp, const unsigned short* __restrict__ vb,
                         float* __restrict__ part) {
    int p = blockIdx.x, ch = blockIdx.y, b = blockIdx.z, d = threadIdx.x;
    const float* kpb = kp + (size_t)b * LSEQ * P;
    const unsigned short* vbp = vb + (size_t)b * LSEQ * D;
    int l0 = ch * 256;
    float acc = 0.f;
    for (int l = l0; l < l0 + 256; l++)
        acc = fmaf(kpb[(size_t)l * P + p], bf2f(vbp[(size_t)l * D + d]), acc);
    part[(((size_t)b * 16 + ch) * P + p) * D + d] = acc;
}

__global__ void k_kvred(const float* __restrict__ part, float* __restrict__ kv) {
    int p = blockIdx.x, b = blockIdx.y, d = threadIdx.x;
    float acc = 0.f;
    for (int ch = 0; ch < 16; ch++)
        acc += part[(((size_t)b * 16 + ch) * P + p) * D + d];
    kv[((size_t)b * P + p) * D + d] = acc;
}

// attn = (qp @ kv) / (sum_p qp + eps); ab = bf16(layernorm(attn)*g+b)
__global__ void k_attnln(const float* __restrict__ qp, const float* __restrict__ kv,
                         const float* __restrict__ lng, const float* __restrict__ lnb,
                         unsigned short* __restrict__ ab) {
    int row = blockIdx.x;
    int b = row >> 12;
    int d = threadIdx.x; // 128
    const float* qpr = qp + (size_t)row * P;
    const float* kvb = kv + (size_t)b * P * D;
    float num = 0.f, zs = 0.f;
    #pragma unroll 8
    for (int p = 0; p < P; p++) {
        float qv = qpr[p];
        zs += qv;
        num = fmaf(qv, kvb[p * D + d], num);
    }
    float attn = num * (1.f / (zs + 1e-8f));
    __shared__ float red[2];
    float s = attn;
    #pragma unroll
    for (int m = 1; m < 64; m <<= 1) s += __shfl_xor(s, m);
    if ((threadIdx.x & 63) == 0) red[threadIdx.x >> 6] = s;
    __syncthreads();
    float mu = (red[0] + red[1]) * (1.f / 128.f);
    __syncthreads();
    float dv = attn - mu;
    float s2 = dv * dv;
    #pragma unroll
    for (int m = 1; m < 64; m <<= 1) s2 += __shfl_xor(s2, m);
    if ((threadIdx.x & 63) == 0) red[threadIdx.x >> 6] = s2;
    __syncthreads();
    float var = (red[0] + red[1]) * (1.f / 128.f);
    float o = dv * rsqrtf(var + 1e-5f) * lng[d] + lnb[d];
    ab[(size_t)row * D + d] = f2bf(o);
}

// tb = bf16(gelu(ab @ W1T^T + b1)); tile 32 x 128, 2 waves, K=128
__global__ __launch_bounds__(128) void k_mm_ffn1(const unsigned short* __restrict__ ab,
                                                 const unsigned short* __restrict__ W1T,
                                                 const float* __restrict__ b1,
                                                 unsigned short* __restrict__ tb) {
    int r0 = blockIdx.y * 32;
    int c0 = blockIdx.x * 128 + (threadIdx.x >> 6) * 64;
    int lane = threadIdx.x & 63;
    int lr = lane & 15;
    int lk = (lane >> 4) * 8;
    const short* Ap = (const short*)ab;
    const short* Bp = (const short*)W1T;
    f32x4_t acc[2][4] = {};
    #pragma unroll
    for (int kc = 0; kc < 4; kc++) {
        bf16x8_t af[2], bfr[4];
        #pragma unroll
        for (int mi = 0; mi < 2; mi++)
            af[mi] = *(const bf16x8_t*)(Ap + (size_t)(r0 + mi * 16 + lr) * D + kc * 32 + lk);
        #pragma unroll
        for (int ni = 0; ni < 4; ni++)
            bfr[ni] = *(const bf16x8_t*)(Bp + (size_t)(c0 + ni * 16 + lr) * D + kc * 32 + lk);
        #pragma unroll
        for (int mi = 0; mi < 2; mi++)
            #pragma unroll
            for (int ni = 0; ni < 4; ni++)
                acc[mi][ni] = __builtin_amdgcn_mfma_f32_16x16x32_bf16(af[mi], bfr[ni], acc[mi][ni], 0, 0, 0);
    }
    int orow = (lane >> 4) * 4;
    #pragma unroll
    for (int mi = 0; mi < 2; mi++)
        #pragma unroll
        for (int ni = 0; ni < 4; ni++) {
            int col = c0 + ni * 16 + lr;
            float bias = b1[col];
            #pragma unroll
            for (int j = 0; j < 4; j++) {
                float x = acc[mi][ni][j] + bias;
                float g = 0.5f * x * (1.f + erff(x * 0.70710678f));
                tb[(size_t)(r0 + mi * 16 + orow + j) * DFF + col] = f2bf(g);
            }
        }
}

// h += tb @ W2T^T + b2; hb = bf16(h). tile 32 x 128, 2 waves, K=512
__global__ __launch_bounds__(128) void k_mm_ffn2(const unsigned short* __restrict__ tb,
                                                 const unsigned short* __restrict__ W2T,
                                                 const float* __restrict__ b2,
                                                 float* __restrict__ h,
                                                 unsigned short* __restrict__ hb) {
    int r0 = blockIdx.x * 32;
    int c0 = (threadIdx.x >> 6) * 64;
    int lane = threadIdx.x & 63;
    int lr = lane & 15;
    int lk = (lane >> 4) * 8;
    const short* Ap = (const short*)tb;
    const short* Bp = (const short*)W2T;
    f32x4_t acc[2][4] = {};
    #pragma unroll 4
    for (int kc = 0; kc < 16; kc++) {
        bf16x8_t af[2], bfr[4];
        #pragma unroll
        for (int mi = 0; mi < 2; mi++)
            af[mi] = *(const bf16x8_t*)(Ap + (size_t)(r0 + mi * 16 + lr) * DFF + kc * 32 + lk);
        #pragma unroll
        for (int ni = 0; ni < 4; ni++)
            bfr[ni] = *(const bf16x8_t*)(Bp + (size_t)(c0 + ni * 16 + lr) * DFF + kc * 32 + lk);
        #pragma unroll
        for (int mi = 0; mi < 2; mi++)
            #pragma unroll
            for (int ni = 0; ni < 4; ni++)
                acc[mi][ni] = __builtin_amdgcn_mfma_f32_16x16x32_bf16(af[mi], bfr[ni], acc[mi][ni], 0, 0, 0);
    }
    int orow = (lane >> 4) * 4;
    #pragma unroll
    for (int mi = 0; mi < 2; mi++)
        #pragma unroll
        for (int ni = 0; ni < 4; ni++) {
            int col = c0 + ni * 16 + lr;
            float bias = b2[col];
            #pragma unroll
            for (int j = 0; j < 4; j++) {
                size_t idx = (size_t)(r0 + mi * 16 + orow + j) * D + col;
                float hn = h[idx] + acc[mi][ni][j] + bias;
                h[idx] = hn;
                hb[idx] = f2bf(hn);
            }
        }
}

// logits = hb(bf16 [M,128]) @ wt^T(bf16 [VOCAB,128]) -> f32 [M,VOCAB]
// 256x256 tile, 8 waves (4 row-groups x 2 col-groups), each wave 64 rows x 128 cols.
// XCD-bijective swizzle (4000 blocks = 8*500), by fastest inside each XCD chunk:
// per XCD L2 working set = all of A (2 MB, reused 15-16x) + ~1 MB B slice (reused 32x).
// Swapped-operand MFMA: mfma(bfr, af) puts 4 consecutive vocab cols of one row in
// each lane's 4 acc regs -> float4 stores (per verified m89/m91 C/D mapping).
__global__ __launch_bounds__(512) void k_gemm_out(const unsigned short* __restrict__ A,
                                                  const unsigned short* __restrict__ Bt,
                                                  float* __restrict__ C) {
    int bid = blockIdx.x;                       // 0..3999
    int swz = (bid & 7) * 500 + (bid >> 3);     // bijective: 4000 = 8*500
    int by = swz & 31;                          // 32 row tiles (fastest)
    int bx = swz >> 5;                          // 125 vocab tiles
    int wid = threadIdx.x >> 6;
    int lane = threadIdx.x & 63;
    int wr = wid >> 1;                          // 0..3
    int wc = wid & 1;                           // 0..1
    int row0 = by * 256 + wr * 64;
    int col0 = bx * 256 + wc * 128;
    int lr = lane & 15;
    int hi = lane >> 4;
    int lk = hi * 8;
    const short* Ap = (const short*)A;
    const short* Bp = (const short*)Bt;
    f32x4_t acc[8][4] = {};                     // [ni][mi]
    #pragma unroll
    for (int kc = 0; kc < 4; kc++) {
        bf16x8_t af[4], bfr[8];
        #pragma unroll
        for (int mi = 0; mi < 4; mi++)
            af[mi] = *(const bf16x8_t*)(Ap + (size_t)(row0 + mi * 16 + lr) * D + kc * 32 + lk);
        #pragma unroll
        for (int ni = 0; ni < 8; ni++)
            bfr[ni] = *(const bf16x8_t*)(Bp + (size_t)(col0 + ni * 16 + lr) * D + kc * 32 + lk);
        #pragma unroll
        for (int ni = 0; ni < 8; ni++)
            #pragma unroll
            for (int mi = 0; mi < 4; mi++)
                acc[ni][mi] = __builtin_amdgcn_mfma_f32_16x16x32_bf16(bfr[ni], af[mi], acc[ni][mi], 0, 0, 0);
    }
    // lane (lr,hi) holds C[row0+mi*16+lr][col0+ni*16+hi*4 .. +3]
    #pragma unroll
    for (int ni = 0; ni < 8; ni++)
        #pragma unroll
        for (int mi = 0; mi < 4; mi++)
            *(f32x4_t*)(C + (size_t)(row0 + mi * 16 + lr) * VOCAB + col0 + ni * 16 + hi * 4) = acc[ni][mi];
}

extern "C" void kernel_launch(void* const* d_in, const int* in_sizes, int n_in,
                              void* d_out, int out_size, void* d_ws, size_t ws_size,
                              hipStream_t stream) {
    const int*   tokens = (const int*)d_in[0];
    const float* embed  = (const float*)d_in[1];
    const float* pos    = (const float*)d_in[2];
    const float* Wq     = (const float*)d_in[3];
    const float* Wk     = (const float*)d_in[4];
    const float* Wv     = (const float*)d_in[5];
    const float* proj   = (const float*)d_in[6];
    const float* lng    = (const float*)d_in[7];
    const float* lnb    = (const float*)d_in[8];
    const float* W1     = (const float*)d_in[9];
    const float* b1     = (const float*)d_in[10];
    const float* W2     = (const float*)d_in[11];
    const float* b2     = (const float*)d_in[12];
    const float* Wout   = (const float*)d_in[13];
    float* out = (float*)d_out;
    char* ws = (char*)d_ws;

    // ws layout (MB offsets)
    float*          h    = (float*)(ws);                               // [0,4)
    unsigned short* hb   = (unsigned short*)(ws + ((size_t)4  << 20)); // [4,6)
    float*          qp   = (float*)(ws + ((size_t)6  << 20));          // [6,8)
    float*          kp   = (float*)(ws + ((size_t)8  << 20));          // [8,10)
    unsigned short* vb   = (unsigned short*)(ws + ((size_t)10 << 20)); // [10,12)
    float*          kvp  = (float*)(ws + ((size_t)12 << 20));          // [12,13) 1MB
    float*          kv   = (float*)(ws + ((size_t)13 << 20));          // 64KB
    unsigned short* ab   = (unsigned short*)(ws + ((size_t)14 << 20)); // [14,16)
    unsigned short* tb   = (unsigned short*)(ws + ((size_t)16 << 20)); // [16,24)
    unsigned short* wt   = (unsigned short*)(ws + ((size_t)24 << 20)); // [24,32)
    unsigned short* bqkv = (unsigned short*)(ws + ((size_t)32 << 20)); // 128KB
    unsigned short* w1t  = (unsigned short*)(ws + ((size_t)33 << 20)); // 256KB
    unsigned short* w2t  = (unsigned short*)(ws + ((size_t)34 << 20)); // 256KB

    k_embed<<<dim3(M * 32 / 256), dim3(256), 0, stream>>>(tokens, embed, pos, h, hb);
    k_wt<<<dim3(VOCAB / 32, D / 32), dim3(32, 8), 0, stream>>>(Wout, wt);
    k_prep_qkv<<<dim3(256, NL), dim3(128), 0, stream>>>(Wq, Wk, Wv, proj, bqkv);
    k_prep_w1t<<<dim3(DFF, NL), dim3(128), 0, stream>>>(W1, w1t);
    k_prep_w2t<<<dim3(D, NL), dim3(512), 0, stream>>>(W2, w2t);

    for (int i = 0; i < NL; i++) {
        k_qkvp<<<dim3(M / 32), dim3(256), 0, stream>>>(hb, bqkv + (size_t)i * 256 * D, qp, kp, vb);
        k_kvpart<<<dim3(P, 16, BATCH), dim3(128), 0, stream>>>(kp, vb, kvp);
        k_kvred<<<dim3(P, BATCH), dim3(128), 0, stream>>>(kvp, kv);
        k_attnln<<<dim3(M), dim3(128), 0, stream>>>(qp, kv, lng + (size_t)i * D, lnb + (size_t)i * D, ab);
        k_mm_ffn1<<<dim3(4, M / 32), dim3(128), 0, stream>>>(ab, w1t + (size_t)i * DFF * D, b1 + (size_t)i * DFF, tb);
        k_mm_ffn2<<<dim3(M / 32), dim3(128), 0, stream>>>(tb, w2t + (size_t)i * D * DFF, b2 + (size_t)i * D, h, hb);
    }

    k_gemm_out<<<dim3((VOCAB / 256) * (M / 256)), dim3(512), 0, stream>>>(hb, wt, out);
}

// Round 2
// 525.007 us; speedup vs baseline: 1.1017x; 1.1017x over previous
//
#include <hip/hip_runtime.h>
#include <hip/hip_bf16.h>

#define BATCH 2
#define LSEQ 4096
#define M (BATCH*LSEQ)   // 8192 rows
#define D 128
#define P 64
#define NL 2
#define VOCAB 32000
#define DFF 512

typedef __attribute__((ext_vector_type(8))) short bf16x8_t;
typedef __attribute__((ext_vector_type(4))) float f32x4_t;

__device__ inline unsigned short f2bf(float f) {
    unsigned int u = __float_as_uint(f);
    unsigned int r = (u + 0x7fffu + ((u >> 16) & 1u)) >> 16;
    return (unsigned short)r;
}
__device__ inline float bf2f(unsigned short u) {
    return __uint_as_float(((unsigned int)u) << 16);
}

// h[row][d] = embed[tokens[row]][d] + pos[row % LSEQ][d]; also hb = bf16(h)
__global__ void k_embed(const int* __restrict__ tokens, const float* __restrict__ embed,
                        const float* __restrict__ pos, float* __restrict__ h,
                        unsigned short* __restrict__ hb) {
    int gid = blockIdx.x * blockDim.x + threadIdx.x;   // over M*32 float4s
    int row = gid >> 5;
    int d4  = gid & 31;
    int l = row & (LSEQ - 1);
    int tok = tokens[row];
    float4 a = ((const float4*)(embed + (size_t)tok * D))[d4];
    float4 b = ((const float4*)(pos + (size_t)l * D))[d4];
    a.x += b.x; a.y += b.y; a.z += b.z; a.w += b.w;
    ((float4*)(h + (size_t)row * D))[d4] = a;
    ushort4 u; u.x = f2bf(a.x); u.y = f2bf(a.y); u.z = f2bf(a.z); u.w = f2bf(a.w);
    ((ushort4*)(hb + (size_t)row * D))[d4] = u;
}

// Wout [D][VOCAB] f32  ->  WT [VOCAB][D] bf16
__global__ void k_wt(const float* __restrict__ W, unsigned short* __restrict__ WT) {
    __shared__ float tile[32][33];
    int v0 = blockIdx.x * 32, d0 = blockIdx.y * 32;
    int tx = threadIdx.x, ty = threadIdx.y;
    for (int i = ty; i < 32; i += 8)
        tile[i][tx] = W[(size_t)(d0 + i) * VOCAB + v0 + tx];
    __syncthreads();
    for (int i = ty; i < 32; i += 8)
        WT[(size_t)(v0 + i) * D + d0 + tx] = f2bf(tile[tx][i]);
}

// BqkvT[l][256][128] bf16:
//  rows 0-63   : WqpT[p][d] = sum_e Wq[l][d][e] * proj[l][e][p]
//  rows 64-127 : WkpT[p][d]
//  rows 128-255: WvT[o][d]  = Wv[l][d][o]
__global__ void k_prep_qkv(const float* __restrict__ Wq, const float* __restrict__ Wk,
                           const float* __restrict__ Wv, const float* __restrict__ proj,
                           unsigned short* __restrict__ out) {
    int r = blockIdx.x;       // 0..255
    int l = blockIdx.y;
    int d = threadIdx.x;      // 128
    const float* WqL = Wq + (size_t)l * D * D;
    const float* WkL = Wk + (size_t)l * D * D;
    const float* WvL = Wv + (size_t)l * D * D;
    const float* pjL = proj + (size_t)l * D * P;
    float val;
    if (r < 128) {
        const float* W = (r < 64) ? WqL : WkL;
        int p = r & 63;
        float s = 0.f;
        for (int e = 0; e < D; e++) s = fmaf(W[d * D + e], pjL[e * P + p], s);
        val = s;
    } else {
        val = WvL[d * D + (r - 128)];
    }
    out[((size_t)l * 256 + r) * D + d] = f2bf(val);
}

// W1T[l][n][d] = W1[l][d][n]  (bf16)
__global__ void k_prep_w1t(const float* __restrict__ W1, unsigned short* __restrict__ W1T) {
    int n = blockIdx.x;   // 512
    int l = blockIdx.y;
    int d = threadIdx.x;  // 128
    W1T[((size_t)l * DFF + n) * D + d] = f2bf(W1[((size_t)l * D + d) * DFF + n]);
}

// W2T[l][n][f] = W2[l][f][n]  (bf16)
__global__ void k_prep_w2t(const float* __restrict__ W2, unsigned short* __restrict__ W2T) {
    int n = blockIdx.x;   // 128
    int l = blockIdx.y;
    int f = threadIdx.x;  // 512
    W2T[((size_t)l * D + n) * DFF + f] = f2bf(W2[((size_t)l * DFF + f) * D + n]);
}

// Fused projections: C[M x 256] = hb @ BqkvT^T ; cols 0-63 -> qp=elu(x)+1 (f32),
// 64-127 -> kp (f32), 128-255 -> vb (bf16). Tile 32 rows x 256 cols, 4 waves.
__global__ __launch_bounds__(256) void k_qkvp(const unsigned short* __restrict__ hb,
                                              const unsigned short* __restrict__ Bt,
                                              float* __restrict__ qp, float* __restrict__ kp,
                                              unsigned short* __restrict__ vb) {
    int r0 = blockIdx.x * 32;
    int wid = threadIdx.x >> 6;
    int lane = threadIdx.x & 63;
    int c0 = wid * 64;
    int lr = lane & 15;
    int lk = (lane >> 4) * 8;
    const short* Ap = (const short*)hb;
    const short* Bp = (const short*)Bt;
    f32x4_t acc[2][4] = {};
    #pragma unroll
    for (int kc = 0; kc < 4; kc++) {
        bf16x8_t af[2], bfr[4];
        #pragma unroll
        for (int mi = 0; mi < 2; mi++)
            af[mi] = *(const bf16x8_t*)(Ap + (size_t)(r0 + mi * 16 + lr) * D + kc * 32 + lk);
        #pragma unroll
        for (int ni = 0; ni < 4; ni++)
            bfr[ni] = *(const bf16x8_t*)(Bp + (size_t)(c0 + ni * 16 + lr) * D + kc * 32 + lk);
        #pragma unroll
        for (int mi = 0; mi < 2; mi++)
            #pragma unroll
            for (int ni = 0; ni < 4; ni++)
                acc[mi][ni] = __builtin_amdgcn_mfma_f32_16x16x32_bf16(af[mi], bfr[ni], acc[mi][ni], 0, 0, 0);
    }
    int orow = (lane >> 4) * 4;
    if (wid < 2) {  // qp / kp with elu(x)+1, f32 out
        float* out = (wid == 0) ? qp : kp;
        #pragma unroll
        for (int mi = 0; mi < 2; mi++)
            #pragma unroll
            for (int ni = 0; ni < 4; ni++)
                #pragma unroll
                for (int j = 0; j < 4; j++) {
                    float x = acc[mi][ni][j];
                    float e = x > 0.f ? x + 1.f : __expf(x);
                    out[(size_t)(r0 + mi * 16 + orow + j) * P + ni * 16 + lr] = e;
                }
    } else {        // vb bf16 out, cols (wid-2)*64 + ...
        int cb = (wid - 2) * 64;
        #pragma unroll
        for (int mi = 0; mi < 2; mi++)
            #pragma unroll
            for (int ni = 0; ni < 4; ni++)
                #pragma unroll
                for (int j = 0; j < 4; j++)
                    vb[(size_t)(r0 + mi * 16 + orow + j) * D + cb + ni * 16 + lr] = f2bf(acc[mi][ni][j]);
    }
}

// partial kv: part[b][ch][p][d] = sum_{l in chunk} kp[b][l][p] * vb[b][l][d]
__global__ void k_kvpart(const float* __restrict__ kp, const unsigned short* __restrict__ vb,
                         float* __restrict__ part) {
    int p = blockIdx.x, ch = blockIdx.y, b = blockIdx.z, d = threadIdx.x;
    const float* kpb = kp + (size_t)b * LSEQ * P;
    const unsigned short* vbp = vb + (size_t)b * LSEQ * D;
    int l0 = ch * 256;
    float acc = 0.f;
    for (int l = l0; l < l0 + 256; l++)
        acc = fmaf(kpb[(size_t)l * P + p], bf2f(vbp[(size_t)l * D + d]), acc);
    part[(((size_t)b * 16 + ch) * P + p) * D + d] = acc;
}

__global__ void k_kvred(const float* __restrict__ part, float* __restrict__ kv) {
    int p = blockIdx.x, b = blockIdx.y, d = threadIdx.x;
    float acc = 0.f;
    for (int ch = 0; ch < 16; ch++)
        acc += part[(((size_t)b * 16 + ch) * P + p) * D + d];
    kv[((size_t)b * P + p) * D + d] = acc;
}

// attn = (qp @ kv) / (sum_p qp + eps); ab = bf16(layernorm(attn)*g+b)
__global__ void k_attnln(const float* __restrict__ qp, const float* __restrict__ kv,
                         const float* __restrict__ lng, const float* __restrict__ lnb,
                         unsigned short* __restrict__ ab) {
    int row = blockIdx.x;
    int b = row >> 12;
    int d = threadIdx.x; // 128
    const float* qpr = qp + (size_t)row * P;
    const float* kvb = kv + (size_t)b * P * D;
    float num = 0.f, zs = 0.f;
    #pragma unroll 8
    for (int p = 0; p < P; p++) {
        float qv = qpr[p];
        zs += qv;
        num = fmaf(qv, kvb[p * D + d], num);
    }
    float attn = num * (1.f / (zs + 1e-8f));
    __shared__ float red[2];
    float s = attn;
    #pragma unroll
    for (int m = 1; m < 64; m <<= 1) s += __shfl_xor(s, m);
    if ((threadIdx.x & 63) == 0) red[threadIdx.x >> 6] = s;
    __syncthreads();
    float mu = (red[0] + red[1]) * (1.f / 128.f);
    __syncthreads();
    float dv = attn - mu;
    float s2 = dv * dv;
    #pragma unroll
    for (int m = 1; m < 64; m <<= 1) s2 += __shfl_xor(s2, m);
    if ((threadIdx.x & 63) == 0) red[threadIdx.x >> 6] = s2;
    __syncthreads();
    float var = (red[0] + red[1]) * (1.f / 128.f);
    float o = dv * rsqrtf(var + 1e-5f) * lng[d] + lnb[d];
    ab[(size_t)row * D + d] = f2bf(o);
}

// tb = bf16(gelu(ab @ W1T^T + b1)); tile 32 x 128, 2 waves, K=128
__global__ __launch_bounds__(128) void k_mm_ffn1(const unsigned short* __restrict__ ab,
                                                 const unsigned short* __restrict__ W1T,
                                                 const float* __restrict__ b1,
                                                 unsigned short* __restrict__ tb) {
    int r0 = blockIdx.y * 32;
    int c0 = blockIdx.x * 128 + (threadIdx.x >> 6) * 64;
    int lane = threadIdx.x & 63;
    int lr = lane & 15;
    int lk = (lane >> 4) * 8;
    const short* Ap = (const short*)ab;
    const short* Bp = (const short*)W1T;
    f32x4_t acc[2][4] = {};
    #pragma unroll
    for (int kc = 0; kc < 4; kc++) {
        bf16x8_t af[2], bfr[4];
        #pragma unroll
        for (int mi = 0; mi < 2; mi++)
            af[mi] = *(const bf16x8_t*)(Ap + (size_t)(r0 + mi * 16 + lr) * D + kc * 32 + lk);
        #pragma unroll
        for (int ni = 0; ni < 4; ni++)
            bfr[ni] = *(const bf16x8_t*)(Bp + (size_t)(c0 + ni * 16 + lr) * D + kc * 32 + lk);
        #pragma unroll
        for (int mi = 0; mi < 2; mi++)
            #pragma unroll
            for (int ni = 0; ni < 4; ni++)
                acc[mi][ni] = __builtin_amdgcn_mfma_f32_16x16x32_bf16(af[mi], bfr[ni], acc[mi][ni], 0, 0, 0);
    }
    int orow = (lane >> 4) * 4;
    #pragma unroll
    for (int mi = 0; mi < 2; mi++)
        #pragma unroll
        for (int ni = 0; ni < 4; ni++) {
            int col = c0 + ni * 16 + lr;
            float bias = b1[col];
            #pragma unroll
            for (int j = 0; j < 4; j++) {
                float x = acc[mi][ni][j] + bias;
                float g = 0.5f * x * (1.f + erff(x * 0.70710678f));
                tb[(size_t)(r0 + mi * 16 + orow + j) * DFF + col] = f2bf(g);
            }
        }
}

// h += tb @ W2T^T + b2; hb = bf16(h). tile 32 x 128, 2 waves, K=512
__global__ __launch_bounds__(128) void k_mm_ffn2(const unsigned short* __restrict__ tb,
                                                 const unsigned short* __restrict__ W2T,
                                                 const float* __restrict__ b2,
                                                 float* __restrict__ h,
                                                 unsigned short* __restrict__ hb) {
    int r0 = blockIdx.x * 32;
    int c0 = (threadIdx.x >> 6) * 64;
    int lane = threadIdx.x & 63;
    int lr = lane & 15;
    int lk = (lane >> 4) * 8;
    const short* Ap = (const short*)tb;
    const short* Bp = (const short*)W2T;
    f32x4_t acc[2][4] = {};
    #pragma unroll 4
    for (int kc = 0; kc < 16; kc++) {
        bf16x8_t af[2], bfr[4];
        #pragma unroll
        for (int mi = 0; mi < 2; mi++)
            af[mi] = *(const bf16x8_t*)(Ap + (size_t)(r0 + mi * 16 + lr) * DFF + kc * 32 + lk);
        #pragma unroll
        for (int ni = 0; ni < 4; ni++)
            bfr[ni] = *(const bf16x8_t*)(Bp + (size_t)(c0 + ni * 16 + lr) * DFF + kc * 32 + lk);
        #pragma unroll
        for (int mi = 0; mi < 2; mi++)
            #pragma unroll
            for (int ni = 0; ni < 4; ni++)
                acc[mi][ni] = __builtin_amdgcn_mfma_f32_16x16x32_bf16(af[mi], bfr[ni], acc[mi][ni], 0, 0, 0);
    }
    int orow = (lane >> 4) * 4;
    #pragma unroll
    for (int mi = 0; mi < 2; mi++)
        #pragma unroll
        for (int ni = 0; ni < 4; ni++) {
            int col = c0 + ni * 16 + lr;
            float bias = b2[col];
            #pragma unroll
            for (int j = 0; j < 4; j++) {
                size_t idx = (size_t)(r0 + mi * 16 + orow + j) * D + col;
                float hn = h[idx] + acc[mi][ni][j] + bias;
                h[idx] = hn;
                hb[idx] = f2bf(hn);
            }
        }
}

// logits = hb(bf16 [M,128]) @ wt^T(bf16 [VOCAB,128]) -> f32 [M,VOCAB]
// 128x128 tile, 4 waves (2x2), acc[4][4] (round-0 occupancy: ~110-130 VGPR,
// 4 waves/SIMD). Two additions vs round-0:
//  - swapped-operand MFMA mfma(bfr, af): lane (lr,hi) holds
//    C[row0+mi*16+lr][col0+ni*16+hi*4 .. +3]  -> float4 stores, 16 store
//    instrs/thread instead of 64 scalar dwords (same 64B segmentation).
//  - bijective XCD swizzle (16000 = 8*2000), row tile (by) fastest inside
//    each XCD chunk: per-XCD L2 set = A (2MB) + ~31-tile B slice (~1MB) < 4MB.
__global__ __launch_bounds__(256) void k_gemm_out(const unsigned short* __restrict__ A,
                                                  const unsigned short* __restrict__ Bt,
                                                  float* __restrict__ C) {
    int bid = blockIdx.x;                       // 0..15999
    int swz = (bid & 7) * 2000 + (bid >> 3);    // bijective: 16000 = 8*2000
    int by = swz & 63;                          // 64 row tiles (fastest)
    int bx = swz >> 6;                          // 250 vocab tiles
    int wid = threadIdx.x >> 6;
    int lane = threadIdx.x & 63;
    int wr = wid >> 1, wc = wid & 1;
    int row0 = by * 128 + wr * 64;
    int col0 = bx * 128 + wc * 64;
    int lr = lane & 15;
    int hi = lane >> 4;
    int lk = hi * 8;
    const short* Ap = (const short*)A;
    const short* Bp = (const short*)Bt;
    f32x4_t acc[4][4] = {};                     // [ni][mi]
    #pragma unroll
    for (int kc = 0; kc < 4; kc++) {
        bf16x8_t af[4], bfr[4];
        #pragma unroll
        for (int mi = 0; mi < 4; mi++)
            af[mi] = *(const bf16x8_t*)(Ap + (size_t)(row0 + mi * 16 + lr) * D + kc * 32 + lk);
        #pragma unroll
        for (int ni = 0; ni < 4; ni++)
            bfr[ni] = *(const bf16x8_t*)(Bp + (size_t)(col0 + ni * 16 + lr) * D + kc * 32 + lk);
        #pragma unroll
        for (int ni = 0; ni < 4; ni++)
            #pragma unroll
            for (int mi = 0; mi < 4; mi++)
                acc[ni][mi] = __builtin_amdgcn_mfma_f32_16x16x32_bf16(bfr[ni], af[mi], acc[ni][mi], 0, 0, 0);
    }
    // lane (lr,hi) holds C[row0+mi*16+lr][col0+ni*16+hi*4 .. +3]
    #pragma unroll
    for (int ni = 0; ni < 4; ni++)
        #pragma unroll
        for (int mi = 0; mi < 4; mi++)
            *(f32x4_t*)(C + (size_t)(row0 + mi * 16 + lr) * VOCAB + col0 + ni * 16 + hi * 4) = acc[ni][mi];
}

extern "C" void kernel_launch(void* const* d_in, const int* in_sizes, int n_in,
                              void* d_out, int out_size, void* d_ws, size_t ws_size,
                              hipStream_t stream) {
    const int*   tokens = (const int*)d_in[0];
    const float* embed  = (const float*)d_in[1];
    const float* pos    = (const float*)d_in[2];
    const float* Wq     = (const float*)d_in[3];
    const float* Wk     = (const float*)d_in[4];
    const float* Wv     = (const float*)d_in[5];
    const float* proj   = (const float*)d_in[6];
    const float* lng    = (const float*)d_in[7];
    const float* lnb    = (const float*)d_in[8];
    const float* W1     = (const float*)d_in[9];
    const float* b1     = (const float*)d_in[10];
    const float* W2     = (const float*)d_in[11];
    const float* b2     = (const float*)d_in[12];
    const float* Wout   = (const float*)d_in[13];
    float* out = (float*)d_out;
    char* ws = (char*)d_ws;

    // ws layout (MB offsets)
    float*          h    = (float*)(ws);                               // [0,4)
    unsigned short* hb   = (unsigned short*)(ws + ((size_t)4  << 20)); // [4,6)
    float*          qp   = (float*)(ws + ((size_t)6  << 20));          // [6,8)
    float*          kp   = (float*)(ws + ((size_t)8  << 20));          // [8,10)
    unsigned short* vb   = (unsigned short*)(ws + ((size_t)10 << 20)); // [10,12)
    float*          kvp  = (float*)(ws + ((size_t)12 << 20));          // [12,13) 1MB
    float*          kv   = (float*)(ws + ((size_t)13 << 20));          // 64KB
    unsigned short* ab   = (unsigned short*)(ws + ((size_t)14 << 20)); // [14,16)
    unsigned short* tb   = (unsigned short*)(ws + ((size_t)16 << 20)); // [16,24)
    unsigned short* wt   = (unsigned short*)(ws + ((size_t)24 << 20)); // [24,32)
    unsigned short* bqkv = (unsigned short*)(ws + ((size_t)32 << 20)); // 128KB
    unsigned short* w1t  = (unsigned short*)(ws + ((size_t)33 << 20)); // 256KB
    unsigned short* w2t  = (unsigned short*)(ws + ((size_t)34 << 20)); // 256KB

    k_embed<<<dim3(M * 32 / 256), dim3(256), 0, stream>>>(tokens, embed, pos, h, hb);
    k_wt<<<dim3(VOCAB / 32, D / 32), dim3(32, 8), 0, stream>>>(Wout, wt);
    k_prep_qkv<<<dim3(256, NL), dim3(128), 0, stream>>>(Wq, Wk, Wv, proj, bqkv);
    k_prep_w1t<<<dim3(DFF, NL), dim3(128), 0, stream>>>(W1, w1t);
    k_prep_w2t<<<dim3(D, NL), dim3(512), 0, stream>>>(W2, w2t);

    for (int i = 0; i < NL; i++) {
        k_qkvp<<<dim3(M / 32), dim3(256), 0, stream>>>(hb, bqkv + (size_t)i * 256 * D, qp, kp, vb);
        k_kvpart<<<dim3(P, 16, BATCH), dim3(128), 0, stream>>>(kp, vb, kvp);
        k_kvred<<<dim3(P, BATCH), dim3(128), 0, stream>>>(kvp, kv);
        k_attnln<<<dim3(M), dim3(128), 0, stream>>>(qp, kv, lng + (size_t)i * D, lnb + (size_t)i * D, ab);
        k_mm_ffn1<<<dim3(4, M / 32), dim3(128), 0, stream>>>(ab, w1t + (size_t)i * DFF * D, b1 + (size_t)i * DFF, tb);
        k_mm_ffn2<<<dim3(M / 32), dim3(128), 0, stream>>>(tb, w2t + (size_t)i * D * DFF, b2 + (size_t)i * D, h, hb);
    }

    k_gemm_out<<<dim3((VOCAB / 128) * (M / 128)), dim3(256), 0, stream>>>(hb, wt, out);
}